// Round 9
// baseline (125.475 us; speedup 1.0000x reference)
//
#include <hip/hip_runtime.h>

#define NB 8
#define NN 512
#define ND 64
#define NKEEP 256
#define PJ 132
#define IPB 8                        // i's per block (x 2 e-halves = 16 waves)
#define WSCALE 2.8853900817779268f   // 2*log2(e): MFMA acc = 2*zeta*log2(e)

#define SELU_SCALE 1.0507009873554805f
#define SELU_ALPHA 1.6732632423543773f

typedef __attribute__((ext_vector_type(8))) short short8;
typedef __attribute__((ext_vector_type(4))) float f32x4;

__device__ __forceinline__ unsigned short f2bf_rne(float f) {
    unsigned u = __float_as_uint(f);
    return (unsigned short)((u + 0x7fffu + ((u >> 16) & 1u)) >> 16);
}
__device__ __forceinline__ float bf2f(unsigned short h) {
    return __uint_as_float(((unsigned)h) << 16);
}

// async global->LDS, 16 bytes per lane; lds dest = wave-uniform base (+lane*16 in HW)
__device__ __forceinline__ void gl2lds16(const unsigned short* g, unsigned short* l) {
    __builtin_amdgcn_global_load_lds(
        (const __attribute__((address_space(1))) unsigned int*)g,
        (__attribute__((address_space(3))) unsigned int*)l,
        16, 0, 0);
}

// Pre-swizzled bf16 hi/lo image of x at 128-row chunk granularity:
// image[b][c][k] == desired LDS content for chunk c (k in [0,8192)).
__global__ __launch_bounds__(256)
void sast_prep_kernel(const float* __restrict__ x,
                      unsigned short* __restrict__ xh,
                      unsigned short* __restrict__ xl)
{
    int f = blockIdx.x * 256 + threadIdx.x;   // one float4 each, 65536 total
    int bb = f >> 13;
    int r  = f & 8191;
    int jg = r >> 4, q = r & 15;
    float4 v = *(const float4*)(x + (bb * NN + jg) * ND + q * 4);
    unsigned short h0 = f2bf_rne(v.x), h1 = f2bf_rne(v.y),
                   h2 = f2bf_rne(v.z), h3 = f2bf_rne(v.w);
    unsigned short l0 = (unsigned short)(__float_as_uint(v.x - bf2f(h0)) >> 16);
    unsigned short l1 = (unsigned short)(__float_as_uint(v.y - bf2f(h1)) >> 16);
    unsigned short l2 = (unsigned short)(__float_as_uint(v.z - bf2f(h2)) >> 16);
    unsigned short l3 = (unsigned short)(__float_as_uint(v.w - bf2f(h3)) >> 16);
    int c = jg >> 7, j = jg & 127;
    int idx = bb * 32768 + c * 8192 + j * 64 + ((q * 4) ^ ((j & 7) << 3));
    *(uint2*)(xh + idx) = make_uint2((unsigned)h0 | ((unsigned)h1 << 16),
                                     (unsigned)h2 | ((unsigned)h3 << 16));
    *(uint2*)(xl + idx) = make_uint2((unsigned)l0 | ((unsigned)l1 << 16),
                                     (unsigned)l2 | ((unsigned)l3 << 16));
}

// One block = 16 waves = 8 i's x 2 e-halves. grid = 8*64, 1024 threads.
// X-chunk LDS image shared across 8 i -> 2 blocks/CU = 32 waves/CU.
// Wave (iw, eh): partial logits over its 32 e; eh=1 publishes partials,
// eh=0 combines -> softmax probs. Agg e-split. W-state 32 regs/wave.
__global__ __launch_bounds__(1024, 4)
void sast_attn_kernel(const float* __restrict__ x,
                      const unsigned short* __restrict__ xh_img,
                      const unsigned short* __restrict__ xl_img,
                      const float* __restrict__ att_w,
                      const float* __restrict__ att_b,
                      const float* __restrict__ att_wt,
                      const float* __restrict__ pwa_w,
                      const float* __restrict__ pwa_b,
                      const float* __restrict__ pwo_w,
                      const float* __restrict__ pwo_b,
                      const float* __restrict__ gma,
                      const float* __restrict__ bta,
                      const float* __restrict__ rmean,
                      const float* __restrict__ rvar,
                      const float* __restrict__ pool_w,
                      const float* __restrict__ pool_b,
                      float* __restrict__ ws_h,
                      float* __restrict__ ws_score)
{
    __shared__ alignas(16) unsigned short Xh[8192];   // 16 KB, swizzled image
    __shared__ alignas(16) unsigned short Xl[8192];   // 16 KB, swizzled image
    __shared__ float probs[IPB * PJ];
    __shared__ float lpP[IPB * PJ];                   // eh=1 logit partials
    __shared__ float xg[IPB * ND];
    __shared__ float aggs[IPB * ND];
    __shared__ float hpart[IPB * ND];
    __shared__ float sinvL[IPB];

    const int tid  = threadIdx.x;
    const int w    = tid >> 6;          // wave 0..15
    const int iw   = w & 7;             // local i
    const int eh   = w >> 3;            // e-half 0/1
    const int lane = tid & 63;
    const int g    = lane >> 4;         // k-group
    const int rr   = lane & 15;
    const int jh2  = lane >> 2;         // agg: j sub-row 0..15
    const int eoh  = lane & 3;          // agg: e-oct within half
    const int b    = blockIdx.x >> 6;
    const int i0   = (blockIdx.x & 63) * IPB;
    const int i    = i0 + iw;

    const unsigned short* xhb = xh_img + b * 32768;
    const unsigned short* xlb = xl_img + b * 32768;

    // ---- stage x_i for the 8 i's ----
    if (tid < IPB * ND) xg[tid] = x[(b * NN + i0 + (tid >> 6)) * ND + (tid & 63)];
    __syncthreads();

    // ---- issue chunk-0 staging (async, overlaps W build) ----
    {
        const int base = w * 512;       // 16 waves x 512 u16 = full image
        gl2lds16(xhb + base + (lane << 3), &Xh[base]);
        gl2lds16(xlb + base + (lane << 3), &Xl[base]);
    }

    // ---- build W_i fragments for THIS e-half: mt = eh*2 + mt2 ----
    short8 Wh[2][2], Wl[2][2];
    #pragma unroll
    for (int mt2 = 0; mt2 < 2; ++mt2) {
        const int mt = eh * 2 + mt2;
        #pragma unroll
        for (int ks = 0; ks < 2; ++ks) {
            #pragma unroll
            for (int t = 0; t < 8; ++t) {
                int d = ks * 32 + g * 8 + t;
                int e = mt * 16 + rr;
                float wv = att_w[d * ND + e] * xg[iw * ND + d] * WSCALE;
                unsigned short hh = f2bf_rne(wv);
                unsigned short ll = (unsigned short)(__float_as_uint(wv - bf2f(hh)) >> 16);
                Wh[mt2][ks][t] = (short)hh;
                Wl[mt2][ks][t] = (short)ll;
            }
        }
    }

    // per-lane scaled bias / folded weight; basep = sum of this lane's attw
    f32x4 attb4[2], mw4[2];
    float basep = 0.f;
    #pragma unroll
    for (int mt2 = 0; mt2 < 2; ++mt2) {
        const int mt = eh * 2 + mt2;
        #pragma unroll
        for (int r = 0; r < 4; ++r) {
            int e = mt * 16 + g * 4 + r;
            float aw = att_wt[e];
            attb4[mt2][r] = att_b[e] * WSCALE;
            mw4[mt2][r]   = -2.0f * aw;
            basep += aw;
        }
    }
    // nLam2 = -log2e * 0.5 * sum_e |attw| over ALL 64 e (uniform, tiny loop)
    float sab = 0.f;
    #pragma unroll
    for (int e4 = 0; e4 < ND; e4 += 4) {
        float4 awv = *(const float4*)(att_wt + e4);
        sab += fabsf(awv.x) + fabsf(awv.y) + fabsf(awv.z) + fabsf(awv.w);
    }
    const float nLam2 = -0.72134752f * sab;

    // fragment base offsets (u16 index), swizzle folded in
    const int swz = (rr & 7) << 3;
    const int fb0 = rr * 64 + ((g * 8) ^ swz);
    const int fb1 = rr * 64 + ((g * 8 + 32) ^ swz);
    const int xorc = ((eh * 4 + eoh) ^ (jh2 & 7)) << 3;   // agg swizzle term

    float ssum = 0.f;
    float lp_own[8];
    float a[8];
    #pragma unroll
    for (int k = 0; k < 8; ++k) a[k] = 0.f;

    __syncthreads();   // drains chunk-0 staging

    for (int c = 0; c < 4; ++c) {
        #pragma unroll
        for (int jt = 0; jt < 8; ++jt) {
            short8 bh0 = *(const short8*)(Xh + fb0 + jt * 1024);
            short8 bh1 = *(const short8*)(Xh + fb1 + jt * 1024);
            short8 bl0 = *(const short8*)(Xl + fb0 + jt * 1024);
            short8 bl1 = *(const short8*)(Xl + fb1 + jt * 1024);
            float lp = basep;
            #pragma unroll
            for (int mt2 = 0; mt2 < 2; ++mt2) {
                f32x4 acc = attb4[mt2];
                acc = __builtin_amdgcn_mfma_f32_16x16x32_bf16(Wh[mt2][0], bh0, acc, 0, 0, 0);
                acc = __builtin_amdgcn_mfma_f32_16x16x32_bf16(Wh[mt2][1], bh1, acc, 0, 0, 0);
                acc = __builtin_amdgcn_mfma_f32_16x16x32_bf16(Wh[mt2][0], bl0, acc, 0, 0, 0);
                acc = __builtin_amdgcn_mfma_f32_16x16x32_bf16(Wh[mt2][1], bl1, acc, 0, 0, 0);
                acc = __builtin_amdgcn_mfma_f32_16x16x32_bf16(Wl[mt2][0], bh0, acc, 0, 0, 0);
                acc = __builtin_amdgcn_mfma_f32_16x16x32_bf16(Wl[mt2][1], bh1, acc, 0, 0, 0);
                f32x4 mw = mw4[mt2];
                float u0 = exp2f(fminf(acc[0], 60.f));
                float u1 = exp2f(fminf(acc[1], 60.f));
                float u2 = exp2f(fminf(acc[2], 60.f));
                float u3 = exp2f(fminf(acc[3], 60.f));
                float n01 = fmaf(mw[0], u1, fmaf(mw[1], u0, mw[0] + mw[1]));
                float d01 = fmaf(u0, u1, 1.0f + (u0 + u1));
                float n23 = fmaf(mw[2], u3, fmaf(mw[3], u2, mw[2] + mw[3]));
                float d23 = fmaf(u2, u3, 1.0f + (u2 + u3));
                lp = fmaf(n01, __builtin_amdgcn_rcpf(d01), lp);
                lp = fmaf(n23, __builtin_amdgcn_rcpf(d23), lp);
            }
            lp += __shfl_xor(lp, 16);
            lp += __shfl_xor(lp, 32);
            if (eh == 0) lp_own[jt] = lp;
            else if (lane < 16) lpP[iw * PJ + jt * 16 + rr] = lp;
        }
        __syncthreads();   // partials visible

        if (eh == 0) {
            if (lane < 16) {
                #pragma unroll
                for (int jt = 0; jt < 8; ++jt) {
                    float t = lp_own[jt] + lpP[iw * PJ + jt * 16 + rr];
                    float p = exp2f(fmaf(t, 0.72134752f, nLam2));
                    probs[iw * PJ + jt * 16 + rr] = p;
                    ssum += p;
                }
            }
            if (c == 3) {
                ssum += __shfl_xor(ssum, 1);
                ssum += __shfl_xor(ssum, 2);
                ssum += __shfl_xor(ssum, 4);
                ssum += __shfl_xor(ssum, 8);
                if (lane == 0) sinvL[iw] = __fdividef(1.0f, ssum);
            }
        }
        __syncthreads();   // probs (+ sinv at c==3) visible

        // ---- agg over this e-half: 8 passes ----
        #define ACC2(u, k0) \
            a[k0]     = fmaf(p, __uint_as_float((u) << 16),         a[k0]); \
            a[k0 + 1] = fmaf(p, __uint_as_float((u) & 0xffff0000u), a[k0 + 1]);
        #pragma unroll 4
        for (int pass = 0; pass < 8; ++pass) {
            const int jl = pass * 16 + jh2;
            float p = probs[iw * PJ + jl];
            const int cb = jl * 64 + xorc;
            uint4 hv = *(const uint4*)(&Xh[cb]);
            uint4 lv = *(const uint4*)(&Xl[cb]);
            ACC2(hv.x, 0) ACC2(hv.y, 2) ACC2(hv.z, 4) ACC2(hv.w, 6)
            ACC2(lv.x, 0) ACC2(lv.y, 2) ACC2(lv.z, 4) ACC2(lv.w, 6)
        }
        #undef ACC2

        if (c < 3) {
            __syncthreads();   // all reads of chunk c done
            const unsigned short* sh = xhb + (c + 1) * 8192;
            const unsigned short* sl = xlb + (c + 1) * 8192;
            const int base = w * 512;
            gl2lds16(sh + base + (lane << 3), &Xh[base]);
            gl2lds16(sl + base + (lane << 3), &Xl[base]);
            __syncthreads();   // drained -> chunk c+1 visible
        }
    }

    // ---- agg butterfly over jh2 bits; lanes jh2==0 publish their 8 e ----
    const float Sinv = sinvL[iw];
    #pragma unroll
    for (int k = 0; k < 8; ++k) {
        a[k] += __shfl_xor(a[k], 4);
        a[k] += __shfl_xor(a[k], 8);
        a[k] += __shfl_xor(a[k], 16);
        a[k] += __shfl_xor(a[k], 32);
    }
    if (jh2 == 0) {
        #pragma unroll
        for (int k = 0; k < 8; ++k)
            aggs[iw * ND + eh * 32 + eoh * 8 + k] = a[k] * Sinv;
    }
    __syncthreads();   // aggs complete

    // ---- h partial over this wave's d-range [eh*32, eh*32+32) ----
    {
        const int e = lane;
        const int d0 = eh * 32;
        float hv = (eh == 0) ? (pwa_b[e] + pwo_b[e]) : 0.f;
        #pragma unroll 4
        for (int d = 0; d < 32; ++d) {
            const int dd = d0 + d;
            hv = fmaf(aggs[iw * ND + dd], pwa_w[dd * ND + e], hv);
            hv = fmaf(xg[iw * ND + dd],  pwo_w[dd * ND + e], hv);
        }
        if (eh == 1) hpart[iw * ND + e] = hv;
        __syncthreads();
        if (eh == 0) {
            hv += hpart[iw * ND + e];
            hv = (hv - rmean[e]) * rsqrtf(rvar[e] + 1e-5f) * gma[e] + bta[e];
            hv = hv > 0.f ? SELU_SCALE * hv
                          : SELU_SCALE * SELU_ALPHA * (__expf(hv) - 1.0f);
            ws_h[(b * NN + i) * ND + e] = hv;
            float sc = hv * pool_w[e];
            #pragma unroll
            for (int msk = 32; msk; msk >>= 1) sc += __shfl_xor(sc, msk);
            if (e == 0)
                ws_score[b * NN + i] = __fdividef(1.0f, 1.0f + __expf(-(sc + pool_b[0])));
        }
    }
}

// One block per batch: exact top-k by stable rank (matches lax.top_k:
// descending values, ties broken by lower index), then gather h*score.
__global__ void sast_topk_kernel(const float* __restrict__ ws_h,
                                 const float* __restrict__ ws_score,
                                 float* __restrict__ out)
{
    __shared__ float s[NN];
    __shared__ int sel[NKEEP];
    const int b = blockIdx.x, tid = threadIdx.x;   // 512 threads
    s[tid] = ws_score[b * NN + tid];
    __syncthreads();
    const float v = s[tid];
    int rank = 0;
    for (int j = 0; j < NN; ++j) {
        float sj = s[j];
        rank += ((sj > v) || (sj == v && j < tid)) ? 1 : 0;
    }
    if (rank < NKEEP) sel[rank] = tid;
    __syncthreads();
    #pragma unroll
    for (int it = 0; it < NKEEP * ND / 512; ++it) {
        int f = it * 512 + tid;
        int k = f >> 6, e = f & 63;
        int j = sel[k];
        out[(b * NKEEP + k) * ND + e] = ws_h[(b * NN + j) * ND + e] * s[j];
    }
}

extern "C" void kernel_launch(void* const* d_in, const int* in_sizes, int n_in,
                              void* d_out, int out_size, void* d_ws, size_t ws_size,
                              hipStream_t stream)
{
    const float* x      = (const float*)d_in[0];
    const float* att_w  = (const float*)d_in[1];
    const float* att_b  = (const float*)d_in[2];
    const float* att_wt = (const float*)d_in[3];
    const float* pwa_w  = (const float*)d_in[4];
    const float* pwa_b  = (const float*)d_in[5];
    const float* pwo_w  = (const float*)d_in[6];
    const float* pwo_b  = (const float*)d_in[7];
    const float* gma    = (const float*)d_in[8];
    const float* bta    = (const float*)d_in[9];
    const float* rmean  = (const float*)d_in[10];
    const float* rvar   = (const float*)d_in[11];
    const float* pool_w = (const float*)d_in[12];
    const float* pool_b = (const float*)d_in[13];
    float* out   = (float*)d_out;
    float* ws_h  = (float*)d_ws;                          // 8*512*64 f32 = 1 MB
    float* ws_sc = ws_h + NB * NN * ND;                   // 8*512 f32
    unsigned short* xh_img = (unsigned short*)(ws_sc + NB * NN);   // 512 KB
    unsigned short* xl_img = xh_img + NB * NN * ND;                // 512 KB

    sast_prep_kernel<<<256, 256, 0, stream>>>(x, xh_img, xl_img);
    sast_attn_kernel<<<NB * 64, 1024, 0, stream>>>(
        x, xh_img, xl_img, att_w, att_b, att_wt, pwa_w, pwa_b, pwo_w, pwo_b,
        gma, bta, rmean, rvar, pool_w, pool_b, ws_h, ws_sc);
    sast_topk_kernel<<<NB, 512, 0, stream>>>(ws_h, ws_sc, out);
}

// Round 10
// 115.164 us; speedup vs baseline: 1.0895x; 1.0895x over previous
//
#include <hip/hip_runtime.h>

#define NB 8
#define NN 512
#define ND 64
#define NKEEP 256
#define PJ 132
#define WSCALE 2.8853900817779268f   // 2*log2(e): MFMA acc = 2*zeta*log2(e)
#define K2 0.72134752f               // log2(e)/2

#define SELU_SCALE 1.0507009873554805f
#define SELU_ALPHA 1.6732632423543773f

typedef __attribute__((ext_vector_type(8))) short short8;
typedef __attribute__((ext_vector_type(4))) float f32x4;

__device__ __forceinline__ unsigned short f2bf_rne(float f) {
    unsigned u = __float_as_uint(f);
    return (unsigned short)((u + 0x7fffu + ((u >> 16) & 1u)) >> 16);
}
__device__ __forceinline__ float bf2f(unsigned short h) {
    return __uint_as_float(((unsigned)h) << 16);
}

// async global->LDS, 16 bytes per lane; lds dest = wave-uniform base (+lane*16 in HW)
__device__ __forceinline__ void gl2lds16(const unsigned short* g, unsigned short* l) {
    __builtin_amdgcn_global_load_lds(
        (const __attribute__((address_space(1))) unsigned int*)g,
        (__attribute__((address_space(3))) unsigned int*)l,
        16, 0, 0);
}
__device__ __forceinline__ void gl2lds16f(const float* g, float* l) {
    __builtin_amdgcn_global_load_lds(
        (const __attribute__((address_space(1))) unsigned int*)g,
        (__attribute__((address_space(3))) unsigned int*)l,
        16, 0, 0);
}

// Pre-swizzled bf16 hi/lo image of x at 128-row chunk granularity.
__global__ __launch_bounds__(256)
void sast_prep_kernel(const float* __restrict__ x,
                      unsigned short* __restrict__ xh,
                      unsigned short* __restrict__ xl)
{
    int f = blockIdx.x * 256 + threadIdx.x;   // one float4 each, 65536 total
    int bb = f >> 13;
    int r  = f & 8191;
    int jg = r >> 4, q = r & 15;
    float4 v = *(const float4*)(x + (bb * NN + jg) * ND + q * 4);
    unsigned short h0 = f2bf_rne(v.x), h1 = f2bf_rne(v.y),
                   h2 = f2bf_rne(v.z), h3 = f2bf_rne(v.w);
    unsigned short l0 = (unsigned short)(__float_as_uint(v.x - bf2f(h0)) >> 16);
    unsigned short l1 = (unsigned short)(__float_as_uint(v.y - bf2f(h1)) >> 16);
    unsigned short l2 = (unsigned short)(__float_as_uint(v.z - bf2f(h2)) >> 16);
    unsigned short l3 = (unsigned short)(__float_as_uint(v.w - bf2f(h3)) >> 16);
    int c = jg >> 7, j = jg & 127;
    int idx = bb * 32768 + c * 8192 + j * 64 + ((q * 4) ^ ((j & 7) << 3));
    *(uint2*)(xh + idx) = make_uint2((unsigned)h0 | ((unsigned)h1 << 16),
                                     (unsigned)h2 | ((unsigned)h3 << 16));
    *(uint2*)(xl + idx) = make_uint2((unsigned)l0 | ((unsigned)l1 << 16),
                                     (unsigned)l2 | ((unsigned)l3 << 16));
}

// Phase 1: symmetric upper-triangle logits. Block (b,P) handles i-sets
// {4P..4P+3} (chunks c>=P/32) and {508-4P..511-4P} (chunks from its start):
// 5 chunk-units per block, balanced. p = exp2(L*K2 + nLam2) stored as u16
// (scale cancels in attn = u/sum(u)). Own rows j>=i0; mirror rows j>=i0+4
// into column block i0 -> exactly-once coverage, race-free.
__global__ __launch_bounds__(512, 4)
void sast_logit_kernel(const float* __restrict__ x,
                       const unsigned short* __restrict__ xh_img,
                       const unsigned short* __restrict__ xl_img,
                       const float* __restrict__ att_w,
                       const float* __restrict__ att_b,
                       const float* __restrict__ att_wt,
                       unsigned short* __restrict__ p_buf)
{
    __shared__ alignas(16) unsigned short Xh[8192];   // 16 KB swizzled image
    __shared__ alignas(16) unsigned short Xl[8192];
    __shared__ float probs[4 * PJ];
    __shared__ float lpP[4 * PJ];
    __shared__ float xg[4 * ND];

    const int tid  = threadIdx.x;
    const int w    = tid >> 6;          // wave 0..7
    const int iw   = w & 3;             // local i
    const int eh   = w >> 2;            // e-half 0/1
    const int lane = tid & 63;
    const int g    = lane >> 4;
    const int rr   = lane & 15;
    const int b    = blockIdx.x >> 6;
    const int P    = blockIdx.x & 63;

    const unsigned short* xhb = xh_img + b * 32768;
    const unsigned short* xlb = xl_img + b * 32768;
    unsigned short* pb = p_buf + b * NN * NN;

    // nLam2 = -log2e * 0.5 * sum_e |attw|
    float sab = 0.f;
    #pragma unroll
    for (int e4 = 0; e4 < ND; e4 += 4) {
        float4 awv = *(const float4*)(att_wt + e4);
        sab += fabsf(awv.x) + fabsf(awv.y) + fabsf(awv.z) + fabsf(awv.w);
    }
    const float nLam2 = -K2 * sab;

    const int swz = (rr & 7) << 3;
    const int fb0 = rr * 64 + ((g * 8) ^ swz);
    const int fb1 = rr * 64 + ((g * 8 + 32) ^ swz);

    int curc = -1;
    for (int s = 0; s < 2; ++s) {
        const int i0 = s ? (508 - 4 * P) : 4 * P;
        const int c0 = i0 >> 7;
        __syncthreads();                 // prior reads done; xg safe to overwrite
        if (tid < 256) xg[tid] = x[(b * NN + i0 + (tid >> 6)) * ND + (tid & 63)];
        __syncthreads();                 // xg visible
        if (c0 != curc) {                // stage first needed chunk (hides under W build)
            const int base = w * 1024;
            gl2lds16(xhb + c0 * 8192 + base +       (lane << 3), &Xh[base]);
            gl2lds16(xhb + c0 * 8192 + base + 512 + (lane << 3), &Xh[base + 512]);
            gl2lds16(xlb + c0 * 8192 + base +       (lane << 3), &Xl[base]);
            gl2lds16(xlb + c0 * 8192 + base + 512 + (lane << 3), &Xl[base + 512]);
            curc = c0;
        }

        // W_i fragments for THIS e-half, hi/lo bf16, x 2log2e
        short8 Wh[2][2], Wl[2][2];
        #pragma unroll
        for (int mt2 = 0; mt2 < 2; ++mt2) {
            const int mt = eh * 2 + mt2;
            #pragma unroll
            for (int ks = 0; ks < 2; ++ks) {
                #pragma unroll
                for (int t = 0; t < 8; ++t) {
                    int d = ks * 32 + g * 8 + t;
                    int e = mt * 16 + rr;
                    float wv = att_w[d * ND + e] * xg[iw * ND + d] * WSCALE;
                    unsigned short hh = f2bf_rne(wv);
                    unsigned short ll = (unsigned short)(__float_as_uint(wv - bf2f(hh)) >> 16);
                    Wh[mt2][ks][t] = (short)hh;
                    Wl[mt2][ks][t] = (short)ll;
                }
            }
        }
        f32x4 attb4[2], mw4[2];
        float basep = 0.f;
        #pragma unroll
        for (int mt2 = 0; mt2 < 2; ++mt2) {
            const int mt = eh * 2 + mt2;
            #pragma unroll
            for (int r = 0; r < 4; ++r) {
                int e = mt * 16 + g * 4 + r;
                float aw = att_wt[e];
                attb4[mt2][r] = att_b[e] * WSCALE;
                mw4[mt2][r]   = -2.0f * aw;
                basep += aw;
            }
        }
        __syncthreads();                 // drains staging

        for (int c = c0; c < 4; ++c) {
            if (c != curc) {             // restage (X untouched since last barrier pair)
                const int base = w * 1024;
                gl2lds16(xhb + c * 8192 + base +       (lane << 3), &Xh[base]);
                gl2lds16(xhb + c * 8192 + base + 512 + (lane << 3), &Xh[base + 512]);
                gl2lds16(xlb + c * 8192 + base +       (lane << 3), &Xl[base]);
                gl2lds16(xlb + c * 8192 + base + 512 + (lane << 3), &Xl[base + 512]);
                __syncthreads();         // drained
                curc = c;
            }
            const int jb = c << 7;

            float lp_own[8];
            #pragma unroll
            for (int jt = 0; jt < 8; ++jt) {
                short8 bh0 = *(const short8*)(Xh + fb0 + jt * 1024);
                short8 bh1 = *(const short8*)(Xh + fb1 + jt * 1024);
                short8 bl0 = *(const short8*)(Xl + fb0 + jt * 1024);
                short8 bl1 = *(const short8*)(Xl + fb1 + jt * 1024);
                float lp = basep;
                #pragma unroll
                for (int mt2 = 0; mt2 < 2; ++mt2) {
                    f32x4 acc = attb4[mt2];
                    acc = __builtin_amdgcn_mfma_f32_16x16x32_bf16(Wh[mt2][0], bh0, acc, 0, 0, 0);
                    acc = __builtin_amdgcn_mfma_f32_16x16x32_bf16(Wh[mt2][1], bh1, acc, 0, 0, 0);
                    acc = __builtin_amdgcn_mfma_f32_16x16x32_bf16(Wh[mt2][0], bl0, acc, 0, 0, 0);
                    acc = __builtin_amdgcn_mfma_f32_16x16x32_bf16(Wh[mt2][1], bl1, acc, 0, 0, 0);
                    acc = __builtin_amdgcn_mfma_f32_16x16x32_bf16(Wl[mt2][0], bh0, acc, 0, 0, 0);
                    acc = __builtin_amdgcn_mfma_f32_16x16x32_bf16(Wl[mt2][1], bh1, acc, 0, 0, 0);
                    f32x4 mw = mw4[mt2];
                    float u0 = exp2f(fminf(acc[0], 60.f));
                    float u1 = exp2f(fminf(acc[1], 60.f));
                    float u2 = exp2f(fminf(acc[2], 60.f));
                    float u3 = exp2f(fminf(acc[3], 60.f));
                    float n01 = fmaf(mw[0], u1, fmaf(mw[1], u0, mw[0] + mw[1]));
                    float d01 = fmaf(u0, u1, 1.0f + (u0 + u1));
                    float n23 = fmaf(mw[2], u3, fmaf(mw[3], u2, mw[2] + mw[3]));
                    float d23 = fmaf(u2, u3, 1.0f + (u2 + u3));
                    lp = fmaf(n01, __builtin_amdgcn_rcpf(d01), lp);
                    lp = fmaf(n23, __builtin_amdgcn_rcpf(d23), lp);
                }
                lp += __shfl_xor(lp, 16);
                lp += __shfl_xor(lp, 32);
                if (eh == 0) lp_own[jt] = lp;
                else if (lane < 16) lpP[iw * PJ + jt * 16 + rr] = lp;
            }
            __syncthreads();             // partials visible (SYNC1)

            if (eh == 0 && lane < 16) {
                #pragma unroll
                for (int jt = 0; jt < 8; ++jt) {
                    float t = lp_own[jt] + lpP[iw * PJ + jt * 16 + rr];
                    probs[iw * PJ + jt * 16 + rr] = exp2f(fmaf(t, K2, nLam2));
                }
            }
            __syncthreads();             // probs visible (SYNC2); lpP free

            // own rows: j >= i0
            {
                const int iw2 = tid >> 7, jl = tid & 127, j = jb + jl;
                if (j >= i0) {
                    float p = fminf(probs[iw2 * PJ + jl], 1.0f);
                    pb[(i0 + iw2) * NN + j] =
                        (unsigned short)__float2uint_rn(p * 65535.f);
                }
            }
            // mirror rows: j >= i0+4, cols i0..i0+3 (uint2 = 4 u16)
            if (tid < 128) {
                const int j2 = jb + tid;
                if (j2 >= i0 + 4) {
                    unsigned u0 = __float2uint_rn(fminf(probs[0 * PJ + tid], 1.0f) * 65535.f);
                    unsigned u1 = __float2uint_rn(fminf(probs[1 * PJ + tid], 1.0f) * 65535.f);
                    unsigned u2 = __float2uint_rn(fminf(probs[2 * PJ + tid], 1.0f) * 65535.f);
                    unsigned u3 = __float2uint_rn(fminf(probs[3 * PJ + tid], 1.0f) * 65535.f);
                    *(uint2*)(&pb[j2 * NN + i0]) =
                        make_uint2(u0 | (u1 << 16), u2 | (u3 << 16));
                }
            }
            // no sync needed: next restage touches only X; probs protected by SYNC1/2
        }
    }
}

// Phase 2: per (b, 8 rows): integer row-sum of u16 probs (exact), agg from
// full-f32 x staged in LDS, then h/BN/SELU/score.
__global__ __launch_bounds__(512, 4)
void sast_agg_kernel(const float* __restrict__ x,
                     const unsigned short* __restrict__ p_buf,
                     const float* __restrict__ pwa_w,
                     const float* __restrict__ pwa_b,
                     const float* __restrict__ pwo_w,
                     const float* __restrict__ pwo_b,
                     const float* __restrict__ gma,
                     const float* __restrict__ bta,
                     const float* __restrict__ rmean,
                     const float* __restrict__ rvar,
                     const float* __restrict__ pool_w,
                     const float* __restrict__ pool_b,
                     float* __restrict__ ws_h,
                     float* __restrict__ ws_score)
{
    __shared__ alignas(16) float Xc[8192];            // 32 KB: 128 j x 64 e
    __shared__ alignas(16) unsigned short prow[4096]; // 8 KB: 8 rows x 512
    __shared__ float xrow[8 * ND];
    __shared__ float aggsh[8 * ND];

    const int tid  = threadIdx.x;
    const int w    = tid >> 6;          // wave = local row
    const int lane = tid & 63;
    const int b    = blockIdx.x >> 6;
    const int i0   = (blockIdx.x & 63) * 8;
    const int i    = i0 + w;
    const float* xb = x + b * NN * ND;

    // stage probs rows + chunk 0 + x_i rows
    gl2lds16(p_buf + (b * NN + i0) * NN + (w << 9) + (lane << 3), &prow[w << 9]);
    #pragma unroll
    for (int r = 0; r < 4; ++r)
        gl2lds16f(xb + w * 1024 + r * 256 + (lane << 2), &Xc[w * 1024 + r * 256]);
    xrow[w * ND + lane] = xb[(i0 + w) * ND + lane];
    __syncthreads();

    // exact integer row sum (512*65535 < 2^25)
    uint4 q = *(const uint4*)(&prow[(w << 9) + (lane << 3)]);
    unsigned us = (q.x & 0xffffu) + (q.x >> 16) + (q.y & 0xffffu) + (q.y >> 16)
                + (q.z & 0xffffu) + (q.z >> 16) + (q.w & 0xffffu) + (q.w >> 16);
    #pragma unroll
    for (int m = 32; m; m >>= 1) us += (unsigned)__shfl_xor((int)us, m);
    const float Sinv = __fdividef(1.0f, (float)us);

    float acc = 0.f;                    // agg for e = lane
    for (int c = 0; c < 4; ++c) {
        if (c) {
            __syncthreads();            // prior chunk reads done
            #pragma unroll
            for (int r = 0; r < 4; ++r)
                gl2lds16f(xb + c * 8192 + w * 1024 + r * 256 + (lane << 2),
                          &Xc[w * 1024 + r * 256]);
            __syncthreads();            // drained
        }
        const int jb = c << 7;
        #pragma unroll 4
        for (int jl = 0; jl < 128; jl += 2) {
            unsigned pu = *(const unsigned*)(&prow[(w << 9) + jb + jl]);
            acc = fmaf((float)(pu & 0xffffu), Xc[jl * 64 + lane], acc);
            acc = fmaf((float)(pu >> 16),     Xc[(jl + 1) * 64 + lane], acc);
        }
    }
    aggsh[w * ND + lane] = acc * Sinv;   // same-wave write->read

    float hv = pwa_b[lane] + pwo_b[lane];
    #pragma unroll 4
    for (int d = 0; d < ND; ++d)
        hv = fmaf(aggsh[w * ND + d], pwa_w[d * ND + lane],
             fmaf(xrow[w * ND + d], pwo_w[d * ND + lane], hv));
    hv = (hv - rmean[lane]) * rsqrtf(rvar[lane] + 1e-5f) * gma[lane] + bta[lane];
    hv = hv > 0.f ? SELU_SCALE * hv
                  : SELU_SCALE * SELU_ALPHA * (__expf(hv) - 1.0f);
    ws_h[(b * NN + i) * ND + lane] = hv;
    float sc = hv * pool_w[lane];
    #pragma unroll
    for (int m = 32; m; m >>= 1) sc += __shfl_xor(sc, m);
    if (lane == 0)
        ws_score[b * NN + i] = __fdividef(1.0f, 1.0f + __expf(-(sc + pool_b[0])));
}

// One block per batch: exact top-k by stable rank (matches lax.top_k).
__global__ void sast_topk_kernel(const float* __restrict__ ws_h,
                                 const float* __restrict__ ws_score,
                                 float* __restrict__ out)
{
    __shared__ float s[NN];
    __shared__ int sel[NKEEP];
    const int b = blockIdx.x, tid = threadIdx.x;   // 512 threads
    s[tid] = ws_score[b * NN + tid];
    __syncthreads();
    const float v = s[tid];
    int rank = 0;
    for (int j = 0; j < NN; ++j) {
        float sj = s[j];
        rank += ((sj > v) || (sj == v && j < tid)) ? 1 : 0;
    }
    if (rank < NKEEP) sel[rank] = tid;
    __syncthreads();
    #pragma unroll
    for (int it = 0; it < NKEEP * ND / 512; ++it) {
        int f = it * 512 + tid;
        int k = f >> 6, e = f & 63;
        int j = sel[k];
        out[(b * NKEEP + k) * ND + e] = ws_h[(b * NN + j) * ND + e] * s[j];
    }
}

extern "C" void kernel_launch(void* const* d_in, const int* in_sizes, int n_in,
                              void* d_out, int out_size, void* d_ws, size_t ws_size,
                              hipStream_t stream)
{
    const float* x      = (const float*)d_in[0];
    const float* att_w  = (const float*)d_in[1];
    const float* att_b  = (const float*)d_in[2];
    const float* att_wt = (const float*)d_in[3];
    const float* pwa_w  = (const float*)d_in[4];
    const float* pwa_b  = (const float*)d_in[5];
    const float* pwo_w  = (const float*)d_in[6];
    const float* pwo_b  = (const float*)d_in[7];
    const float* gma    = (const float*)d_in[8];
    const float* bta    = (const float*)d_in[9];
    const float* rmean  = (const float*)d_in[10];
    const float* rvar   = (const float*)d_in[11];
    const float* pool_w = (const float*)d_in[12];
    const float* pool_b = (const float*)d_in[13];
    float* out   = (float*)d_out;
    float* ws_h  = (float*)d_ws;                          // 1 MB
    float* ws_sc = ws_h + NB * NN * ND;                   // 16 KB
    unsigned short* xh_img = (unsigned short*)(ws_sc + NB * NN);   // 512 KB
    unsigned short* xl_img = xh_img + NB * NN * ND;                // 512 KB
    unsigned short* p_buf  = xl_img + NB * NN * ND;                // 4 MB u16

    sast_prep_kernel<<<256, 256, 0, stream>>>(x, xh_img, xl_img);
    sast_logit_kernel<<<NB * 64, 512, 0, stream>>>(
        x, xh_img, xl_img, att_w, att_b, att_wt, p_buf);
    sast_agg_kernel<<<NB * 64, 512, 0, stream>>>(
        x, p_buf, pwa_w, pwa_b, pwo_w, pwo_b,
        gma, bta, rmean, rvar, pool_w, pool_b, ws_h, ws_sc);
    sast_topk_kernel<<<NB, 512, 0, stream>>>(ws_h, ws_sc, out);
}

// Round 11
// 102.205 us; speedup vs baseline: 1.2277x; 1.1268x over previous
//
#include <hip/hip_runtime.h>

#define NB 8
#define NN 512
#define ND 64
#define NKEEP 256
#define PJ 132
#define WSCALE 2.8853900817779268f   // 2*log2(e): MFMA acc = 2*zeta*log2(e)
#define K2 0.72134752f               // log2(e)/2

#define SELU_SCALE 1.0507009873554805f
#define SELU_ALPHA 1.6732632423543773f

typedef __attribute__((ext_vector_type(8))) short short8;
typedef __attribute__((ext_vector_type(4))) float f32x4;

__device__ __forceinline__ unsigned short f2bf_rne(float f) {
    unsigned u = __float_as_uint(f);
    return (unsigned short)((u + 0x7fffu + ((u >> 16) & 1u)) >> 16);
}
__device__ __forceinline__ float bf2f(unsigned short h) {
    return __uint_as_float(((unsigned)h) << 16);
}

// async global->LDS, 16 bytes per lane; lds dest = wave-uniform base (+lane*16 in HW)
__device__ __forceinline__ void gl2lds16(const unsigned short* g, unsigned short* l) {
    __builtin_amdgcn_global_load_lds(
        (const __attribute__((address_space(1))) unsigned int*)g,
        (__attribute__((address_space(3))) unsigned int*)l,
        16, 0, 0);
}
__device__ __forceinline__ void gl2lds16f(const float* g, float* l) {
    __builtin_amdgcn_global_load_lds(
        (const __attribute__((address_space(1))) unsigned int*)g,
        (__attribute__((address_space(3))) unsigned int*)l,
        16, 0, 0);
}

// Pre-swizzled bf16 hi/lo image of x at 128-row chunk granularity.
__global__ __launch_bounds__(256)
void sast_prep_kernel(const float* __restrict__ x,
                      unsigned short* __restrict__ xh,
                      unsigned short* __restrict__ xl)
{
    int f = blockIdx.x * 256 + threadIdx.x;   // one float4 each, 65536 total
    int bb = f >> 13;
    int r  = f & 8191;
    int jg = r >> 4, q = r & 15;
    float4 v = *(const float4*)(x + (bb * NN + jg) * ND + q * 4);
    unsigned short h0 = f2bf_rne(v.x), h1 = f2bf_rne(v.y),
                   h2 = f2bf_rne(v.z), h3 = f2bf_rne(v.w);
    unsigned short l0 = (unsigned short)(__float_as_uint(v.x - bf2f(h0)) >> 16);
    unsigned short l1 = (unsigned short)(__float_as_uint(v.y - bf2f(h1)) >> 16);
    unsigned short l2 = (unsigned short)(__float_as_uint(v.z - bf2f(h2)) >> 16);
    unsigned short l3 = (unsigned short)(__float_as_uint(v.w - bf2f(h3)) >> 16);
    int c = jg >> 7, j = jg & 127;
    int idx = bb * 32768 + c * 8192 + j * 64 + ((q * 4) ^ ((j & 7) << 3));
    *(uint2*)(xh + idx) = make_uint2((unsigned)h0 | ((unsigned)h1 << 16),
                                     (unsigned)h2 | ((unsigned)h3 << 16));
    *(uint2*)(xl + idx) = make_uint2((unsigned)l0 | ((unsigned)l1 << 16),
                                     (unsigned)l2 | ((unsigned)l3 << 16));
}

// Phase 1: upper-triangle logits only. Block (b,P) handles i-sets {4P..4P+3}
// and {508-4P..511-4P} (5 chunk-units, balanced). p = exp2(L*K2+nLam2) as u16
// (scale cancels in attn = u/sum u). ONLY own rows j>=i0 are written
// (coalesced); the lower triangle is reconstructed by phase 2 via transpose
// reads. jt-tiles fully below the boundary are skipped (jt0).
__global__ __launch_bounds__(512, 4)
void sast_logit_kernel(const float* __restrict__ x,
                       const unsigned short* __restrict__ xh_img,
                       const unsigned short* __restrict__ xl_img,
                       const float* __restrict__ att_w,
                       const float* __restrict__ att_b,
                       const float* __restrict__ att_wt,
                       unsigned short* __restrict__ p_buf)
{
    __shared__ alignas(16) unsigned short Xh[8192];   // 16 KB swizzled image
    __shared__ alignas(16) unsigned short Xl[8192];
    __shared__ float probs[4 * PJ];
    __shared__ float lpP[4 * PJ];
    __shared__ float xg[4 * ND];

    const int tid  = threadIdx.x;
    const int w    = tid >> 6;          // wave 0..7
    const int iw   = w & 3;             // local i
    const int eh   = w >> 2;            // e-half 0/1
    const int lane = tid & 63;
    const int g    = lane >> 4;
    const int rr   = lane & 15;
    const int b    = blockIdx.x >> 6;
    const int P    = blockIdx.x & 63;

    const unsigned short* xhb = xh_img + b * 32768;
    const unsigned short* xlb = xl_img + b * 32768;
    unsigned short* pb = p_buf + b * NN * NN;

    // nLam2 = -log2e * 0.5 * sum_e |attw|
    float sab = 0.f;
    #pragma unroll
    for (int e4 = 0; e4 < ND; e4 += 4) {
        float4 awv = *(const float4*)(att_wt + e4);
        sab += fabsf(awv.x) + fabsf(awv.y) + fabsf(awv.z) + fabsf(awv.w);
    }
    const float nLam2 = -K2 * sab;

    const int swz = (rr & 7) << 3;
    const int fb0 = rr * 64 + ((g * 8) ^ swz);
    const int fb1 = rr * 64 + ((g * 8 + 32) ^ swz);

    int curc = -1;
    for (int s = 0; s < 2; ++s) {
        const int i0 = s ? (508 - 4 * P) : 4 * P;
        const int c0 = i0 >> 7;
        __syncthreads();                 // prior reads done; xg safe to overwrite
        if (tid < 256) xg[tid] = x[(b * NN + i0 + (tid >> 6)) * ND + (tid & 63)];
        __syncthreads();                 // xg visible
        if (c0 != curc) {                // stage first needed chunk (hides under W build)
            const int base = w * 1024;
            gl2lds16(xhb + c0 * 8192 + base +       (lane << 3), &Xh[base]);
            gl2lds16(xhb + c0 * 8192 + base + 512 + (lane << 3), &Xh[base + 512]);
            gl2lds16(xlb + c0 * 8192 + base +       (lane << 3), &Xl[base]);
            gl2lds16(xlb + c0 * 8192 + base + 512 + (lane << 3), &Xl[base + 512]);
            curc = c0;
        }

        // W_i fragments for THIS e-half, hi/lo bf16, x 2log2e
        short8 Wh[2][2], Wl[2][2];
        #pragma unroll
        for (int mt2 = 0; mt2 < 2; ++mt2) {
            const int mt = eh * 2 + mt2;
            #pragma unroll
            for (int ks = 0; ks < 2; ++ks) {
                #pragma unroll
                for (int t = 0; t < 8; ++t) {
                    int d = ks * 32 + g * 8 + t;
                    int e = mt * 16 + rr;
                    float wv = att_w[d * ND + e] * xg[iw * ND + d] * WSCALE;
                    unsigned short hh = f2bf_rne(wv);
                    unsigned short ll = (unsigned short)(__float_as_uint(wv - bf2f(hh)) >> 16);
                    Wh[mt2][ks][t] = (short)hh;
                    Wl[mt2][ks][t] = (short)ll;
                }
            }
        }
        f32x4 attb4[2], mw4[2];
        float basep = 0.f;
        #pragma unroll
        for (int mt2 = 0; mt2 < 2; ++mt2) {
            const int mt = eh * 2 + mt2;
            #pragma unroll
            for (int r = 0; r < 4; ++r) {
                int e = mt * 16 + g * 4 + r;
                float aw = att_wt[e];
                attb4[mt2][r] = att_b[e] * WSCALE;
                mw4[mt2][r]   = -2.0f * aw;
                basep += aw;
            }
        }
        __syncthreads();                 // drains staging

        for (int c = c0; c < 4; ++c) {
            if (c != curc) {             // restage (X reads all happened pre-SYNC1)
                const int base = w * 1024;
                gl2lds16(xhb + c * 8192 + base +       (lane << 3), &Xh[base]);
                gl2lds16(xhb + c * 8192 + base + 512 + (lane << 3), &Xh[base + 512]);
                gl2lds16(xlb + c * 8192 + base +       (lane << 3), &Xl[base]);
                gl2lds16(xlb + c * 8192 + base + 512 + (lane << 3), &Xl[base + 512]);
                __syncthreads();         // drained
                curc = c;
            }
            const int jb = c << 7;
            const int jt0 = (i0 > jb) ? ((i0 - jb) >> 4) : 0;  // skip tiles below boundary

            float lp_own[8];
            #pragma unroll
            for (int jt = jt0; jt < 8; ++jt) {
                short8 bh0 = *(const short8*)(Xh + fb0 + jt * 1024);
                short8 bh1 = *(const short8*)(Xh + fb1 + jt * 1024);
                short8 bl0 = *(const short8*)(Xl + fb0 + jt * 1024);
                short8 bl1 = *(const short8*)(Xl + fb1 + jt * 1024);
                float lp = basep;
                #pragma unroll
                for (int mt2 = 0; mt2 < 2; ++mt2) {
                    f32x4 acc = attb4[mt2];
                    acc = __builtin_amdgcn_mfma_f32_16x16x32_bf16(Wh[mt2][0], bh0, acc, 0, 0, 0);
                    acc = __builtin_amdgcn_mfma_f32_16x16x32_bf16(Wh[mt2][1], bh1, acc, 0, 0, 0);
                    acc = __builtin_amdgcn_mfma_f32_16x16x32_bf16(Wh[mt2][0], bl0, acc, 0, 0, 0);
                    acc = __builtin_amdgcn_mfma_f32_16x16x32_bf16(Wh[mt2][1], bl1, acc, 0, 0, 0);
                    acc = __builtin_amdgcn_mfma_f32_16x16x32_bf16(Wl[mt2][0], bh0, acc, 0, 0, 0);
                    acc = __builtin_amdgcn_mfma_f32_16x16x32_bf16(Wl[mt2][1], bh1, acc, 0, 0, 0);
                    f32x4 mw = mw4[mt2];
                    float u0 = exp2f(fminf(acc[0], 60.f));
                    float u1 = exp2f(fminf(acc[1], 60.f));
                    float u2 = exp2f(fminf(acc[2], 60.f));
                    float u3 = exp2f(fminf(acc[3], 60.f));
                    float n01 = fmaf(mw[0], u1, fmaf(mw[1], u0, mw[0] + mw[1]));
                    float d01 = fmaf(u0, u1, 1.0f + (u0 + u1));
                    float n23 = fmaf(mw[2], u3, fmaf(mw[3], u2, mw[2] + mw[3]));
                    float d23 = fmaf(u2, u3, 1.0f + (u2 + u3));
                    lp = fmaf(n01, __builtin_amdgcn_rcpf(d01), lp);
                    lp = fmaf(n23, __builtin_amdgcn_rcpf(d23), lp);
                }
                lp += __shfl_xor(lp, 16);
                lp += __shfl_xor(lp, 32);
                if (eh == 0) lp_own[jt] = lp;
                else if (lane < 16) lpP[iw * PJ + jt * 16 + rr] = lp;
            }
            __syncthreads();             // partials visible (SYNC1)

            if (eh == 0 && lane < 16) {
                #pragma unroll
                for (int jt = jt0; jt < 8; ++jt) {
                    float t = lp_own[jt] + lpP[iw * PJ + jt * 16 + rr];
                    probs[iw * PJ + jt * 16 + rr] = exp2f(fmaf(t, K2, nLam2));
                }
            }
            __syncthreads();             // probs visible (SYNC2); lpP free

            // own rows only: j >= i0, coalesced 256B runs
            {
                const int iw2 = tid >> 7, jl = tid & 127, j = jb + jl;
                if (j >= i0) {
                    float p = fminf(probs[iw2 * PJ + jl], 1.0f);
                    pb[(i0 + iw2) * NN + j] =
                        (unsigned short)__float2uint_rn(p * 65535.f);
                }
            }
            // no extra sync: next restage touches only X; probs guarded by SYNC1/2
        }
    }
}

// Phase 2: per (b, 8 rows): rebuild full prob row (own row + transpose
// prefix), exact integer row-sum, agg from full-f32 x staged in LDS, then
// h/BN/SELU/score.
__global__ __launch_bounds__(512, 4)
void sast_agg_kernel(const float* __restrict__ x,
                     const unsigned short* __restrict__ p_buf,
                     const float* __restrict__ pwa_w,
                     const float* __restrict__ pwa_b,
                     const float* __restrict__ pwo_w,
                     const float* __restrict__ pwo_b,
                     const float* __restrict__ gma,
                     const float* __restrict__ bta,
                     const float* __restrict__ rmean,
                     const float* __restrict__ rvar,
                     const float* __restrict__ pool_w,
                     const float* __restrict__ pool_b,
                     float* __restrict__ ws_h,
                     float* __restrict__ ws_score)
{
    __shared__ alignas(16) float Xc[8192];             // 32 KB: 128 j x 64 e
    __shared__ alignas(16) unsigned short prow[4096];  // 8 KB: 8 rows x 512
    __shared__ alignas(16) unsigned short pcolT[4096]; // 8 KB: 512 j x 8 cols
    __shared__ float xrow[8 * ND];
    __shared__ float aggsh[8 * ND];

    const int tid  = threadIdx.x;
    const int w    = tid >> 6;          // wave = local row
    const int lane = tid & 63;
    const int b    = blockIdx.x >> 6;
    const int i0   = (blockIdx.x & 63) * 8;
    const int i    = i0 + w;
    const float* xb = x + b * NN * ND;
    const unsigned short* pbb = p_buf + b * NN * NN;

    // stage own prob rows + transpose stripe + chunk 0 of x + x_i rows
    gl2lds16(pbb + (i0 + w) * NN + (lane << 3), &prow[w << 9]);
    if (tid < i0 + 4)                    // p[t][i0..i0+7], 16B aligned (i0 % 8 == 0)
        *(uint4*)(&pcolT[tid * 8]) = *(const uint4*)(pbb + tid * NN + i0);
    #pragma unroll
    for (int r = 0; r < 4; ++r)
        gl2lds16f(xb + w * 1024 + r * 256 + (lane << 2), &Xc[w * 1024 + r * 256]);
    xrow[w * ND + lane] = xb[i * ND + lane];
    __syncthreads();                     // drains gl2lds + pcolT/xrow writes

    // overlay transpose prefix into own row (same-wave write->read below)
    const int B = i0 + ((w >= 4) ? 4 : 0);   // row i's own-data boundary
    for (int j = lane; j < B; j += 64)
        prow[(w << 9) + j] = pcolT[j * 8 + w];

    // exact integer row sum (512*65535 < 2^25)
    uint4 q = *(const uint4*)(&prow[(w << 9) + (lane << 3)]);
    unsigned us = (q.x & 0xffffu) + (q.x >> 16) + (q.y & 0xffffu) + (q.y >> 16)
                + (q.z & 0xffffu) + (q.z >> 16) + (q.w & 0xffffu) + (q.w >> 16);
    #pragma unroll
    for (int m = 32; m; m >>= 1) us += (unsigned)__shfl_xor((int)us, m);
    const float Sinv = __fdividef(1.0f, (float)us);

    float acc = 0.f;                    // agg for e = lane
    for (int c = 0; c < 4; ++c) {
        if (c) {
            __syncthreads();            // prior chunk reads done
            #pragma unroll
            for (int r = 0; r < 4; ++r)
                gl2lds16f(xb + c * 8192 + w * 1024 + r * 256 + (lane << 2),
                          &Xc[w * 1024 + r * 256]);
            __syncthreads();            // drained
        }
        const int jb = c << 7;
        #pragma unroll 4
        for (int jl = 0; jl < 128; jl += 2) {
            unsigned pu = *(const unsigned*)(&prow[(w << 9) + jb + jl]);
            acc = fmaf((float)(pu & 0xffffu), Xc[jl * 64 + lane], acc);
            acc = fmaf((float)(pu >> 16),     Xc[(jl + 1) * 64 + lane], acc);
        }
    }
    aggsh[w * ND + lane] = acc * Sinv;   // same-wave write->read

    float hv = pwa_b[lane] + pwo_b[lane];
    #pragma unroll 4
    for (int d = 0; d < ND; ++d)
        hv = fmaf(aggsh[w * ND + d], pwa_w[d * ND + lane],
             fmaf(xrow[w * ND + d], pwo_w[d * ND + lane], hv));
    hv = (hv - rmean[lane]) * rsqrtf(rvar[lane] + 1e-5f) * gma[lane] + bta[lane];
    hv = hv > 0.f ? SELU_SCALE * hv
                  : SELU_SCALE * SELU_ALPHA * (__expf(hv) - 1.0f);
    ws_h[(b * NN + i) * ND + lane] = hv;
    float sc = hv * pool_w[lane];
    #pragma unroll
    for (int m = 32; m; m >>= 1) sc += __shfl_xor(sc, m);
    if (lane == 0)
        ws_score[b * NN + i] = __fdividef(1.0f, 1.0f + __expf(-(sc + pool_b[0])));
}

// One block per batch: exact top-k by stable rank (matches lax.top_k).
__global__ void sast_topk_kernel(const float* __restrict__ ws_h,
                                 const float* __restrict__ ws_score,
                                 float* __restrict__ out)
{
    __shared__ float s[NN];
    __shared__ int sel[NKEEP];
    const int b = blockIdx.x, tid = threadIdx.x;   // 512 threads
    s[tid] = ws_score[b * NN + tid];
    __syncthreads();
    const float v = s[tid];
    int rank = 0;
    for (int j = 0; j < NN; ++j) {
        float sj = s[j];
        rank += ((sj > v) || (sj == v && j < tid)) ? 1 : 0;
    }
    if (rank < NKEEP) sel[rank] = tid;
    __syncthreads();
    #pragma unroll
    for (int it = 0; it < NKEEP * ND / 512; ++it) {
        int f = it * 512 + tid;
        int k = f >> 6, e = f & 63;
        int j = sel[k];
        out[(b * NKEEP + k) * ND + e] = ws_h[(b * NN + j) * ND + e] * s[j];
    }
}

extern "C" void kernel_launch(void* const* d_in, const int* in_sizes, int n_in,
                              void* d_out, int out_size, void* d_ws, size_t ws_size,
                              hipStream_t stream)
{
    const float* x      = (const float*)d_in[0];
    const float* att_w  = (const float*)d_in[1];
    const float* att_b  = (const float*)d_in[2];
    const float* att_wt = (const float*)d_in[3];
    const float* pwa_w  = (const float*)d_in[4];
    const float* pwa_b  = (const float*)d_in[5];
    const float* pwo_w  = (const float*)d_in[6];
    const float* pwo_b  = (const float*)d_in[7];
    const float* gma    = (const float*)d_in[8];
    const float* bta    = (const float*)d_in[9];
    const float* rmean  = (const float*)d_in[10];
    const float* rvar   = (const float*)d_in[11];
    const float* pool_w = (const float*)d_in[12];
    const float* pool_b = (const float*)d_in[13];
    float* out   = (float*)d_out;
    float* ws_h  = (float*)d_ws;                          // 1 MB
    float* ws_sc = ws_h + NB * NN * ND;                   // 16 KB
    unsigned short* xh_img = (unsigned short*)(ws_sc + NB * NN);   // 512 KB
    unsigned short* xl_img = xh_img + NB * NN * ND;                // 512 KB
    unsigned short* p_buf  = xl_img + NB * NN * ND;                // 4 MB u16

    sast_prep_kernel<<<256, 256, 0, stream>>>(x, xh_img, xl_img);
    sast_logit_kernel<<<NB * 64, 512, 0, stream>>>(
        x, xh_img, xl_img, att_w, att_b, att_wt, p_buf);
    sast_agg_kernel<<<NB * 64, 512, 0, stream>>>(
        x, p_buf, pwa_w, pwa_b, pwo_w, pwo_b,
        gma, bta, rmean, rvar, pool_w, pool_b, ws_h, ws_sc);
    sast_topk_kernel<<<NB, 512, 0, stream>>>(ws_h, ws_sc, out);
}